// Round 2
// baseline (277.295 us; speedup 1.0000x reference)
//
#include <hip/hip_runtime.h>

// Problem constants from the reference
#define NB 64
#define NU 9
#define NV 9
#define UV 81          // NU*NV
#define HWSZ 9216      // 96*96
#define MDISP 4

typedef float f32x2 __attribute__((ext_vector_type(2)));

// Two-pass, low-register streaming kernel. Each thread owns 2 adjacent pixels
// (float2 loads -> 512 B per wave per plane, fully coalesced).
// Pass A: running max + argmax only (~12 live VGPRs).
// Pass B: re-read (LLC/L2-warm: whole 191 MB input < 256 MB Infinity Cache),
//         accumulate global + windowed sums with known max/center.
__global__ __launch_bounds__(256) void vcn_kernel(const float* __restrict__ x,
                                                  float* __restrict__ out) {
    int tid = blockIdx.x * blockDim.x + threadIdx.x;
    int pix = tid * 2;                 // first of this thread's 2 pixels
    int b   = pix / HWSZ;              // 9216 even -> pair never straddles b
    int hw  = pix - b * HWSZ;

    const f32x2* xp = (const f32x2*)(x + (size_t)b * UV * HWSZ + hw);
    const int PSTR = HWSZ / 2;         // plane stride in f32x2 units

    // ---- Pass A: max + argmax (first-occurrence ties, matching jnp.argmax) ----
    float m0 = -1e30f, m1 = -1e30f;
    int   i0 = 0,      i1 = 0;
#pragma unroll
    for (int i = 0; i < UV; ++i) {
        f32x2 v = xp[(size_t)i * PSTR];
        if (v.x > m0) { m0 = v.x; i0 = i; }
        if (v.y > m1) { m1 = v.y; i1 = i; }
    }

    int uc0 = i0 / NV, vc0 = i0 - uc0 * NV;
    int uc1 = i1 / NV, vc1 = i1 - uc1 * NV;

    // ---- Pass B: accumulate sums ----
    float seg0 = 0.f, sxg0 = 0.f, sel0 = 0.f, sxl0 = 0.f, sfx0 = 0.f, sfy0 = 0.f;
    float seg1 = 0.f, sxg1 = 0.f, sel1 = 0.f, sxl1 = 0.f, sfx1 = 0.f, sfy1 = 0.f;
#pragma unroll
    for (int u = 0; u < NU; ++u) {
        bool ur0 = (u >= uc0 - 3) & (u <= uc0 + 3);
        bool ur1 = (u >= uc1 - 3) & (u <= uc1 + 3);
        float fu = (float)(u - MDISP);
#pragma unroll
        for (int w = 0; w < NV; ++w) {
            f32x2 v = xp[(size_t)(u * NV + w) * PSTR];
            float fv = (float)(w - MDISP);

            // pixel 0
            {
                float t = v.x - m0;
                float e = __expf(t);
                seg0 += e;
                sxg0 += e * t;
                bool in = ur0 & (w >= vc0 - 3) & (w <= vc0 + 3);
                float e0 = in ? e : 0.f;
                sel0 += e0;
                sxl0 += e0 * t;
                sfx0 += e0 * fu;
                sfy0 += e0 * fv;
            }
            // pixel 1
            {
                float t = v.y - m1;
                float e = __expf(t);
                seg1 += e;
                sxg1 += e * t;
                bool in = ur1 & (w >= vc1 - 3) & (w <= vc1 + 3);
                float e1 = in ? e : 0.f;
                sel1 += e1;
                sxl1 += e1 * t;
                sfx1 += e1 * fu;
                sfy1 += e1 * fv;
            }
        }
    }

    // entropy = log(Z) - E[x-m]; normalize by 1/ln(49), 1/ln(81)
    const float KLOC = 0.25694895f;    // 1/ln(49)
    const float KGLO = 0.22754075f;    // 1/ln(81)

    float il0 = 1.f / sel0, ig0 = 1.f / seg0;
    float il1 = 1.f / sel1, ig1 = 1.f / seg1;

    f32x2 outx, outy, lent, gent;
    outx.x = sfx0 * il0;                       outx.y = sfx1 * il1;
    outy.x = sfy0 * il0;                       outy.y = sfy1 * il1;
    lent.x = (__logf(sel0) - sxl0 * il0) * KLOC; lent.y = (__logf(sel1) - sxl1 * il1) * KLOC;
    gent.x = (__logf(seg0) - sxg0 * ig0) * KGLO; gent.y = (__logf(seg1) - sxg1 * ig1) * KGLO;

    f32x2* op = (f32x2*)(out + (size_t)b * 4 * HWSZ + hw);
    op[0 * PSTR] = outx;
    op[1 * PSTR] = outy;
    op[2 * PSTR] = lent;
    op[3 * PSTR] = gent;
}

extern "C" void kernel_launch(void* const* d_in, const int* in_sizes, int n_in,
                              void* d_out, int out_size, void* d_ws, size_t ws_size,
                              hipStream_t stream) {
    const float* x = (const float*)d_in[0];
    float* out = (float*)d_out;
    const int total_threads = NB * HWSZ / 2;   // 294912 (2 pixels/thread)
    const int block = 256;
    const int grid = total_threads / block;    // 1152
    vcn_kernel<<<grid, block, 0, stream>>>(x, out);
}